// Round 7
// baseline (349.440 us; speedup 1.0000x reference)
//
#include <hip/hip_runtime.h>
#include <hip/hip_bf16.h>
#include <math.h>

typedef unsigned short ushort_t;
typedef unsigned int uint_t;
typedef __attribute__((ext_vector_type(8))) short short8;
typedef __attribute__((ext_vector_type(4))) float floatx4;
typedef __attribute__((ext_vector_type(2))) uint_t uint2v;
typedef __attribute__((ext_vector_type(4))) uint_t uint4v;

#define BB 4
#define TT 2048
#define CCH 1024
#define HH 16
#define HDIM 64
#define MROWS (BB * TT) /* 8192 */

#define GLDS(g, l)                                                        \
  __builtin_amdgcn_global_load_lds(                                       \
      (const __attribute__((address_space(1))) void*)(g),                 \
      (__attribute__((address_space(3))) void*)(l), 16, 0, 0)

#if __has_builtin(__builtin_amdgcn_exp2f)
#define EXP2(x) __builtin_amdgcn_exp2f(x)
#else
#define EXP2(x) exp2f(x)
#endif

__device__ __forceinline__ ushort_t f2bf(float f) {
  union { float f; uint_t u; } x;
  x.f = f;
  uint_t u = x.u;
  u += 0x7FFFu + ((u >> 16) & 1u); // RNE
  return (ushort_t)(u >> 16);
}

__device__ __forceinline__ float bf2f(ushort_t v) {
  union { uint_t u; float f; } x;
  x.u = ((uint_t)v) << 16;
  return x.f;
}

// truncating bf16 pair pack (low = a, high = b); |err| <= 2^-8 relative
__device__ __forceinline__ uint_t pk_trunc(float a, float b) {
  union { float f; uint_t u; } xa, xb;
  xa.f = a; xb.f = b;
  return (xa.u >> 16) | (xb.u & 0xFFFF0000u);
}

__device__ __forceinline__ uint_t pk_rne(float a, float b) {
  return (uint_t)f2bf(a) | ((uint_t)f2bf(b) << 16);
}

// ---------------------------------------------------------------------------
// dtype detector: flag=1 iff x's words look like packed bf16 pairs.
// ---------------------------------------------------------------------------
__global__ void detect_dtype(const uint_t* __restrict__ x, uint_t* __restrict__ flag) {
  __shared__ int cnt;
  if (threadIdx.x == 0) cnt = 0;
  __syncthreads();
  int c = 0;
  for (int i = threadIdx.x; i < 1024; i += 256) {
    uint_t w = x[i];
    uint_t e = (w >> 7) & 0xFFu;
    if (e >= 100u && e <= 150u) c++;
  }
  atomicAdd(&cnt, c);
  __syncthreads();
  if (threadIdx.x == 0) *flag = (cnt > 512) ? 1u : 0u;
}

// x -> canonical bf16 xb [8192,1024]
__global__ void prep_x(const void* __restrict__ x, ushort_t* __restrict__ xb,
                       const uint_t* __restrict__ flag, int n) {
  int i = blockIdx.x * 256 + threadIdx.x;
  if (i >= n) return;
  if (*flag)
    xb[i] = ((const ushort_t*)x)[i];
  else
    xb[i] = f2bf(((const float*)x)[i]);
}

// ---------------------------------------------------------------------------
// tiled transpose+cast: src [1024][N] -> dst bf16 [N][1024]
// ---------------------------------------------------------------------------
__global__ __launch_bounds__(256) void prep_wT(const void* __restrict__ w,
                                               ushort_t* __restrict__ wT,
                                               const uint_t* __restrict__ flag,
                                               int N) {
  __shared__ float tile[64][65];
  const int tid = threadIdx.x;
  const int bn = blockIdx.x * 64;
  const int bk = blockIdx.y * 64;
  if (*flag == 0) {
    const float* src = (const float*)w;
#pragma unroll
    for (int p = 0; p < 4; p++) {
      int r = p * 16 + (tid >> 4);
      int c = (tid & 15) * 4;
      float4 v = *(const float4*)&src[(size_t)(bk + r) * N + bn + c];
      tile[r][c] = v.x; tile[r][c + 1] = v.y;
      tile[r][c + 2] = v.z; tile[r][c + 3] = v.w;
    }
  } else {
    const ushort_t* src = (const ushort_t*)w;
#pragma unroll
    for (int p = 0; p < 4; p++) {
      int r = p * 16 + (tid >> 4);
      int c = (tid & 15) * 4;
      const ushort_t* s = &src[(size_t)(bk + r) * N + bn + c];
      tile[r][c] = bf2f(s[0]); tile[r][c + 1] = bf2f(s[1]);
      tile[r][c + 2] = bf2f(s[2]); tile[r][c + 3] = bf2f(s[3]);
    }
  }
  __syncthreads();
#pragma unroll
  for (int p = 0; p < 8; p++) {
    int nn = p * 8 + (tid >> 5);
    int kk = (tid & 31) * 2;
    uint_t u = pk_rne(tile[kk][nn], tile[kk + 1][nn]);
    *(uint_t*)&wT[(size_t)(bn + nn) * 1024 + bk + kk] = u;
  }
}

// ---------------------------------------------------------------------------
// V transpose: vb [B,H,T,64] -> vtb [B,H,64,T]; 64x64 LDS tiles, coalesced
// global on both sides. HBM-bound (~32 MB total).
// ---------------------------------------------------------------------------
__global__ __launch_bounds__(256) void transpose_v(
    const ushort_t* __restrict__ vb, ushort_t* __restrict__ vtb) {
  __shared__ ushort_t t[64][72];
  const int tid = threadIdx.x;
  const int bh = blockIdx.y;
  const int t0 = blockIdx.x * 64;
  const ushort_t* src = vb + ((size_t)bh * TT + t0) * HDIM;
  ushort_t* dst = vtb + (size_t)bh * HDIM * TT + t0;
#pragma unroll
  for (int p = 0; p < 2; p++) {
    int c = tid + p * 256;
    int row = c >> 3, col = (c & 7) * 8; // row = t-local, col = d
    short8 v = *(const short8*)&src[row * 64 + col];
#pragma unroll
    for (int j = 0; j < 8; j++) t[col + j][row] = (ushort_t)v[j]; // t[d][tloc]
  }
  __syncthreads();
#pragma unroll
  for (int p = 0; p < 2; p++) {
    int c = tid + p * 256;
    int row = c >> 3, col = (c & 7) * 8; // row = d, col = t-local
    short8 v = *(const short8*)&t[row][col];
    *(short8*)&dst[(size_t)row * TT + col] = v;
  }
}

// ---------------------------------------------------------------------------
// copy yout (ws scratch) -> d_out; element size per flag (bf16=2B, fp32=4B).
// ---------------------------------------------------------------------------
__global__ void copy_out(const uint4v* __restrict__ yout, uint4v* __restrict__ dout,
                         const uint_t* __restrict__ flag, int out_size) {
  size_t n16 = (size_t)out_size * ((*flag) ? 2u : 4u) / 16u;
  for (size_t i = blockIdx.x * 256 + threadIdx.x; i < n16;
       i += (size_t)gridDim.x * 256)
    dout[i] = yout[i];
}

// ---------------------------------------------------------------------------
// GEMM C[M,N] = A[M,K=1024] @ Bt[N,K=1024]^T (+bias[N]), 128x128 tile,
// 4 waves (2x2), mfma_f32_16x16x32_bf16, global_load_lds 16B staging.
// MODE 0: scatter Q/K/V all coalesced [B,H,T,64].
// MODE 1: write out (dtype per flag).
// ---------------------------------------------------------------------------
template <int MODE>
__global__ __launch_bounds__(256) void gemm_bt(
    const ushort_t* __restrict__ A, const ushort_t* __restrict__ Bt,
    const void* __restrict__ bias,
    ushort_t* __restrict__ q_out, ushort_t* __restrict__ k_out,
    ushort_t* __restrict__ v_out, void* __restrict__ outp,
    const uint_t* __restrict__ flag) {
  alignas(16) __shared__ ushort_t As[128 * 32];
  alignas(16) __shared__ ushort_t Bs[128 * 32];

  const int tid = threadIdx.x;
  const int wave = tid >> 6, lane = tid & 63;
  const int quad = lane >> 4, l16 = lane & 15;
  const int wm = (wave & 1) * 64, wn = (wave >> 1) * 64;
  const int bm = blockIdx.x * 128, bn = blockIdx.y * 128;

  floatx4 acc[4][4] = {};

  for (int k0 = 0; k0 < 1024; k0 += 32) {
#pragma unroll
    for (int s = 0; s < 2; s++) {
      int c = tid + s * 256;
      int row = c >> 2, cc = (c & 3) * 8;
      GLDS(&A[(size_t)(bm + row) * 1024 + k0 + cc], &As[c * 8]);
      GLDS(&Bt[(size_t)(bn + row) * 1024 + k0 + cc], &Bs[c * 8]);
    }
    __syncthreads();

    short8 af[4], bf[4];
#pragma unroll
    for (int i = 0; i < 4; i++)
      af[i] = *(const short8*)&As[(wm + i * 16 + l16) * 32 + quad * 8];
#pragma unroll
    for (int i = 0; i < 4; i++)
      bf[i] = *(const short8*)&Bs[(wn + i * 16 + l16) * 32 + quad * 8];

#pragma unroll
    for (int mi = 0; mi < 4; mi++)
#pragma unroll
      for (int ni = 0; ni < 4; ni++)
        acc[mi][ni] = __builtin_amdgcn_mfma_f32_16x16x32_bf16(
            af[mi], bf[ni], acc[mi][ni], 0, 0, 0);
    __syncthreads();
  }

  const bool inbf = (*flag != 0);

#pragma unroll
  for (int mi = 0; mi < 4; mi++) {
#pragma unroll
    for (int ni = 0; ni < 4; ni++) {
#pragma unroll
      for (int r = 0; r < 4; r++) {
        int row = bm + wm + mi * 16 + quad * 4 + r;
        int col = bn + wn + ni * 16 + l16;
        float bsv = inbf ? bf2f(((const ushort_t*)bias)[col])
                         : ((const float*)bias)[col];
        float v = acc[mi][ni][r] + bsv;
        if (MODE == 0) {
          ushort_t bv = f2bf(v);
          int b = row >> 11, t = row & 2047;
          int which = col >> 10, rem = col & 1023;
          int h = rem >> 6, d = rem & 63;
          size_t bh = (size_t)(b * HH + h);
          ushort_t* dst = (which == 0) ? q_out : (which == 1) ? k_out : v_out;
          dst[(bh * TT + t) * HDIM + d] = bv; // all coalesced [B,H,T,64]
        } else {
          size_t idx = (size_t)row * CCH + col;
          if (inbf)
            ((ushort_t*)outp)[idx] = f2bf(v);
          else
            ((float*)outp)[idx] = v;
        }
      }
    }
  }
}

// ---------------------------------------------------------------------------
// Flash attention v4 (unchanged core): operand-swapped MFMAs, per-lane
// softmax, work-balanced strip pairs, GLDS+XOR-swizzle K/V staging.
// Q,K: [B,H,T,64]. Vt: [B,H,64,T]. Out attb: [B,T,H*64] bf16.
// ---------------------------------------------------------------------------
__global__ __launch_bounds__(256) void flash_attn(
    const ushort_t* __restrict__ qb, const ushort_t* __restrict__ kb,
    const ushort_t* __restrict__ vtb, ushort_t* __restrict__ attb) {
  alignas(16) __shared__ ushort_t Ks[64 * 64];
  alignas(16) __shared__ ushort_t Vs[64 * 64];
  alignas(16) __shared__ ushort_t Ps[4][32 * 72];

  const int tid = threadIdx.x;
  const int wave = tid >> 6, lane = tid & 63;
  const int quad = lane >> 4, l16 = lane & 15;
  const int bh = blockIdx.y;
  const int b = bh >> 4, h = bh & 15;
  const int qtL = blockIdx.x;  // 0..7
  const int qtH = 15 - qtL;    // 8..15
  const int qbL = qtL * 128 + wave * 32;
  const int qbH = qtH * 128 + wave * 32;

  const ushort_t* Q = qb + (size_t)bh * TT * HDIM;
  const ushort_t* K = kb + (size_t)bh * TT * HDIM;
  const ushort_t* Vt = vtb + (size_t)bh * HDIM * TT;
  ushort_t* Pw = Ps[wave];

  const float SC = 0.015625f * 1.44269504089f; // (1/64)*log2(e)

  short8 qfL[2][2], qfH[2][2];
#pragma unroll
  for (int m = 0; m < 2; m++)
#pragma unroll
    for (int ks = 0; ks < 2; ks++) {
      short8 a = *(const short8*)&Q[(size_t)(qbL + m * 16 + l16) * HDIM +
                                    ks * 32 + quad * 8];
      short8 c = *(const short8*)&Q[(size_t)(qbH + m * 16 + l16) * HDIM +
                                    ks * 32 + quad * 8];
#pragma unroll
      for (int j = 0; j < 8; j++) {
        a[j] = (short)f2bf(bf2f((ushort_t)a[j]) * SC);
        c[j] = (short)f2bf(bf2f((ushort_t)c[j]) * SC);
      }
      qfL[m][ks] = a;
      qfH[m][ks] = c;
    }

  floatx4 oL[2][4] = {}, oH[2][4] = {};
  float lsL[2] = {0.f, 0.f}, lsH[2] = {0.f, 0.f};

  const int ltL = (qbL + 31) >> 6, ltH = (qbH + 31) >> 6;
  const int ntiles = 2 * qtH + 2;
  int kt0 = 0;
  short8 kf[4][2];

  auto strip = [&](const short8 (&qf)[2][2], floatx4 (&o)[2][4],
                   float (&ls)[2], int qbs) {
#pragma unroll
    for (int m = 0; m < 2; m++) {
      floatx4 s[4] = {};
#pragma unroll
      for (int sub = 0; sub < 4; sub++)
#pragma unroll
        for (int ks = 0; ks < 2; ks++)
          s[sub] = __builtin_amdgcn_mfma_f32_16x16x32_bf16(
              kf[sub][ks], qf[m][ks], s[sub], 0, 0, 0); // S^T tile

      const bool full = (kt0 + 63 <= qbs + m * 16);
      const int qrow = qbs + m * 16 + l16;
      float part = 0.0f;
#pragma unroll
      for (int sub = 0; sub < 4; sub++) {
#pragma unroll
        for (int r = 0; r < 4; r++) {
          float p = EXP2(s[sub][r]);
          if (!full) {
            int key = kt0 + sub * 16 + quad * 4 + r;
            p = (key <= qrow) ? p : 0.0f;
          }
          s[sub][r] = p;
          part += p;
        }
        uint2v u;
        u[0] = pk_trunc(s[sub][0], s[sub][1]);
        u[1] = pk_trunc(s[sub][2], s[sub][3]);
        *(uint2v*)&Pw[(m * 16 + l16) * 72 + sub * 16 + quad * 4] = u;
      }
      ls[m] += part;
    }

    short8 pf[2][2];
#pragma unroll
    for (int m = 0; m < 2; m++)
#pragma unroll
      for (int ks = 0; ks < 2; ks++)
        pf[m][ks] =
            *(const short8*)&Pw[(m * 16 + l16) * 72 + ks * 32 + quad * 8];

#pragma unroll
    for (int n = 0; n < 4; n++) {
#pragma unroll
      for (int ks = 0; ks < 2; ks++) {
        int col = (ks * 32 + quad * 8) ^ ((l16 & 7) * 8);
        short8 vf = *(const short8*)&Vs[(n * 16 + l16) * 64 + col];
#pragma unroll
        for (int m = 0; m < 2; m++)
          o[m][n] = __builtin_amdgcn_mfma_f32_16x16x32_bf16(
              vf, pf[m][ks], o[m][n], 0, 0, 0); // O^T tile
      }
    }
  };

  for (int kt = 0; kt < ntiles; kt++) {
    kt0 = kt * 64;
    __syncthreads();
#pragma unroll
    for (int s2 = 0; s2 < 2; s2++) {
      int c = tid + s2 * 256;
      int row = c >> 3, gc = ((c & 7) ^ (row & 7)) * 8;
      GLDS(&K[(size_t)(kt0 + row) * HDIM + gc], &Ks[c * 8]);
      GLDS(&Vt[(size_t)row * TT + kt0 + gc], &Vs[c * 8]);
    }
    __syncthreads();

#pragma unroll
    for (int sub = 0; sub < 4; sub++)
#pragma unroll
      for (int ks = 0; ks < 2; ks++) {
        int col = (ks * 32 + quad * 8) ^ ((l16 & 7) * 8);
        kf[sub][ks] = *(const short8*)&Ks[(sub * 16 + l16) * 64 + col];
      }

    if (kt <= ltH) strip(qfH, oH, lsH, qbH);
    if (kt <= ltL) strip(qfL, oL, lsL, qbL);
  }

#pragma unroll
  for (int st = 0; st < 2; st++) {
    floatx4(&o)[2][4] = st ? oL : oH;
    float(&ls)[2] = st ? lsL : lsH;
    const int qbs = st ? qbL : qbH;
#pragma unroll
    for (int m = 0; m < 2; m++) {
      float l = ls[m];
      l += __shfl_xor(l, 16);
      l += __shfl_xor(l, 32);
      float inv = 1.0f / l;
      ushort_t* base =
          &attb[((size_t)(b * TT + qbs + m * 16 + l16)) * CCH + h * HDIM];
#pragma unroll
      for (int n = 0; n < 4; n++) {
        uint2v u;
        u[0] = pk_rne(o[m][n][0] * inv, o[m][n][1] * inv);
        u[1] = pk_rne(o[m][n][2] * inv, o[m][n][3] * inv);
        *(uint2v*)&base[n * 16 + quad * 4] = u;
      }
    }
  }
}

// ---------------------------------------------------------------------------
// Workspace (ushort elements), 58.7 MB total — proven-safe size:
//   xb [8192,1024]      @ 0            (8,388,608)   } same region,
//   vtb [B,H,64,T]      @ 0            (8,388,608)   } sequential lifetimes
//   wqkvT  [3072,1024]  @ 8,388,608    (3,145,728)
//   wprojT [1024,1024]  @ 11,534,336   (1,048,576)
//   qb     [B,H,T,64]   @ 12,582,912   (8,388,608)  } qb/kb dead by gemm<1>;
//   kb     [B,H,T,64]   @ 20,971,520   (8,388,608)  } yout (<=33.5MB fp32)
//   flag   (uint)       @ 29,360,128                  reuses bytes 25.2M..58.7M
// d_out staging: vb [B,H,T,64] (gemm<0>), then attb [B,T,C] (flash/gemm<1>).
// ---------------------------------------------------------------------------
extern "C" void kernel_launch(void* const* d_in, const int* in_sizes, int n_in,
                              void* d_out, int out_size, void* d_ws, size_t ws_size,
                              hipStream_t stream) {
  const void* x      = d_in[0];
  const void* w_qkv  = d_in[1];
  const void* b_qkv  = d_in[2];
  const void* w_proj = d_in[3];
  const void* b_proj = d_in[4];

  ushort_t* ws = (ushort_t*)d_ws;
  ushort_t* xb     = ws;
  ushort_t* vtb    = ws;               // reuses xb region (xb dead)
  ushort_t* wqkvT  = ws + 8388608;
  ushort_t* wprojT = ws + 11534336;
  ushort_t* qb     = ws + 12582912;
  ushort_t* kb     = ws + 20971520;
  uint_t*   flag   = (uint_t*)(ws + 29360128);
  void*     yout   = (void*)(ws + 12582912); // qb/kb region, dead by gemm<1>
  ushort_t* vb     = (ushort_t*)d_out;       // coalesced V staging
  ushort_t* attb   = (ushort_t*)d_out;       // vb dead after transpose_v

  detect_dtype<<<dim3(1), dim3(256), 0, stream>>>((const uint_t*)x, flag);

  prep_x<<<dim3((MROWS * CCH) / 256), dim3(256), 0, stream>>>(
      x, xb, flag, MROWS * CCH);
  prep_wT<<<dim3(48, 16), dim3(256), 0, stream>>>(w_qkv, wqkvT, flag, 3 * CCH);
  prep_wT<<<dim3(16, 16), dim3(256), 0, stream>>>(w_proj, wprojT, flag, CCH);

  gemm_bt<0><<<dim3(MROWS / 128, (3 * CCH) / 128), dim3(256), 0, stream>>>(
      xb, wqkvT, b_qkv, qb, kb, vb, nullptr, flag);

  transpose_v<<<dim3(TT / 64, BB * HH), dim3(256), 0, stream>>>(vb, vtb);

  flash_attn<<<dim3(8, BB * HH), dim3(256), 0, stream>>>(qb, kb, vtb, attb);

  gemm_bt<1><<<dim3(MROWS / 128, CCH / 128), dim3(256), 0, stream>>>(
      attb, wprojT, b_proj, nullptr, nullptr, nullptr, yout, flag);

  copy_out<<<dim3(4096), dim3(256), 0, stream>>>(
      (const uint4v*)yout, (uint4v*)d_out, flag, out_size);
}